// Round 2
// baseline (18.309 us; speedup 1.0000x reference)
//
#include <hip/hip_runtime.h>

#define NN 128
#define PB 136   // bf16 pitch: 272 B/row -> 16B-aligned frags, 8-row bank cycle (2-way max)

typedef __attribute__((ext_vector_type(8))) short short8;
typedef __attribute__((ext_vector_type(4))) float f32x4;

static __device__ __forceinline__ unsigned short f2bf(float x) {
    union { float f; unsigned u; } a; a.f = x;
    unsigned r = a.u + 0x7fffu + ((a.u >> 16) & 1u);   // RNE
    return (unsigned short)(r >> 16);
}
static __device__ __forceinline__ float bf2f(unsigned short h) {
    union { float f; unsigned u; } a; a.u = ((unsigned)h) << 16;
    return a.f;
}

// Fused GAT attention, hi/lo-bf16 MFMA PV.
// grid = 64t * 4 i-blocks, block = 256 (4 waves)
__global__ __launch_bounds__(256, 1) void gat_fused(
    const float* __restrict__ A, const float* __restrict__ W,
    const float* __restrict__ b, float* __restrict__ out)
{
    __shared__ unsigned short Ah_s[NN * PB];   // bf16 hi of A[t,f,j]
    __shared__ unsigned short Al_s[NN * PB];   // bf16 lo residual
    __shared__ unsigned short ah_s[32 * PB];   // bf16 hi of alpha
    __shared__ unsigned short al_s[32 * PB];   // bf16 lo residual
    __shared__ float w_s[2 * NN];
    __shared__ float s1_s[NN], s2_s[NN];
    __shared__ float part_s[8 * NN];           // s1/s2 per-wave partials

    const int tid = threadIdx.x;
    const int t  = blockIdx.x >> 2;
    const int i0 = (blockIdx.x & 3) * 32;
    const float* At = A + (size_t)t * NN * NN;
    const float b0 = b[0];

    if (tid < 64)
        reinterpret_cast<float4*>(w_s)[tid] = reinterpret_cast<const float4*>(W)[tid];
    __syncthreads();

    // ---- stage A[t]: fp32 -> (hi,lo) bf16 LDS; fuse s1/s2 partial sums (fp32) ----
    {
        const float4* A4 = reinterpret_cast<const float4*>(At);
        float p1[4] = {0,0,0,0}, p2[4] = {0,0,0,0};
        #pragma unroll
        for (int it = 0; it < 16; ++it) {
            int e4 = it * 256 + tid;
            int f  = e4 >> 5;                 // A row index (k in s1/s2 terms)
            int j  = (e4 & 31) << 2;          // column
            float4 v = A4[e4];
            float w1f = w_s[f], w2f = w_s[NN + f];
            p1[0] += w1f * v.x; p1[1] += w1f * v.y; p1[2] += w1f * v.z; p1[3] += w1f * v.w;
            p2[0] += w2f * v.x; p2[1] += w2f * v.y; p2[2] += w2f * v.z; p2[3] += w2f * v.w;
            unsigned short h0 = f2bf(v.x), h1 = f2bf(v.y), h2 = f2bf(v.z), h3 = f2bf(v.w);
            unsigned short l0 = f2bf(v.x - bf2f(h0)), l1 = f2bf(v.y - bf2f(h1));
            unsigned short l2 = f2bf(v.z - bf2f(h2)), l3 = f2bf(v.w - bf2f(h3));
            uint2 hv, lv;
            hv.x = (unsigned)h0 | ((unsigned)h1 << 16);
            hv.y = (unsigned)h2 | ((unsigned)h3 << 16);
            lv.x = (unsigned)l0 | ((unsigned)l1 << 16);
            lv.y = (unsigned)l2 | ((unsigned)l3 << 16);
            *reinterpret_cast<uint2*>(&Ah_s[f * PB + j]) = hv;
            *reinterpret_cast<uint2*>(&Al_s[f * PB + j]) = lv;
        }
        // lanes l and l^32 covered disjoint row sets of the same columns
        #pragma unroll
        for (int q = 0; q < 4; ++q) {
            p1[q] += __shfl_xor(p1[q], 32);
            p2[q] += __shfl_xor(p2[q], 32);
        }
        int lane = tid & 63, wid = tid >> 6;
        if (lane < 32) {
            #pragma unroll
            for (int q = 0; q < 4; ++q) {
                part_s[wid * NN + lane * 4 + q]          = p1[q];
                part_s[4 * NN + wid * NN + lane * 4 + q] = p2[q];
            }
        }
    }
    __syncthreads();
    if (tid < NN) {
        s1_s[tid] = part_s[tid] + part_s[NN + tid] + part_s[2 * NN + tid] + part_s[3 * NN + tid];
        s2_s[tid] = part_s[4 * NN + tid] + part_s[5 * NN + tid] + part_s[6 * NN + tid] + part_s[7 * NN + tid];
    }
    __syncthreads();

    // ---- softmax rows i0..i0+31 (8 lanes/row, 16 cols/lane); store alpha hi/lo bf16 ----
    {
        int r  = tid >> 3;
        int jj = tid & 7;
        float s1v = s1_s[i0 + r] + b0;
        float ev[16];
        float m = -3.4e38f;
        #pragma unroll
        for (int c = 0; c < 16; ++c) {
            float x = s1v + s2_s[jj * 16 + c];
            x = (x >= 0.f) ? x : 0.2f * x;
            ev[c] = x;
            m = fmaxf(m, x);
        }
        m = fmaxf(m, __shfl_xor(m, 1));
        m = fmaxf(m, __shfl_xor(m, 2));
        m = fmaxf(m, __shfl_xor(m, 4));
        float s = 0.f;
        #pragma unroll
        for (int c = 0; c < 16; ++c) { ev[c] = __expf(ev[c] - m); s += ev[c]; }
        s += __shfl_xor(s, 1);
        s += __shfl_xor(s, 2);
        s += __shfl_xor(s, 4);
        float inv = 1.0f / s;
        unsigned short* hp = &ah_s[r * PB + jj * 16];
        unsigned short* lp = &al_s[r * PB + jj * 16];
        #pragma unroll
        for (int c = 0; c < 16; c += 2) {
            float v0 = ev[c] * inv, v1 = ev[c + 1] * inv;
            unsigned short h0 = f2bf(v0), h1 = f2bf(v1);
            unsigned short l0 = f2bf(v0 - bf2f(h0)), l1 = f2bf(v1 - bf2f(h1));
            *reinterpret_cast<unsigned*>(hp + c) = (unsigned)h0 | ((unsigned)h1 << 16);
            *reinterpret_cast<unsigned*>(lp + c) = (unsigned)l0 | ((unsigned)l1 << 16);
        }
    }
    __syncthreads();

    // ---- PV via MFMA: out(32 x 128) = alpha(32 x 128) @ B(128 x 128), B[j,f]=A[t,f,j]
    // 3 passes: ah*Ah + ah*Al + al*Ah  (al*Al ~ 2^-18, dropped)
    {
        int lane = tid & 63, wid = tid >> 6;
        int f0  = wid * 32;               // wave's 32 output cols
        int row = lane & 15;
        int kg  = (lane >> 4) * 8;        // k sub-group
        f32x4 acc00 = {0.f,0.f,0.f,0.f}, acc01 = {0.f,0.f,0.f,0.f};
        f32x4 acc10 = {0.f,0.f,0.f,0.f}, acc11 = {0.f,0.f,0.f,0.f};
        const unsigned short* aps[3] = { ah_s, ah_s, al_s };
        const unsigned short* bps[3] = { Ah_s, Al_s, Ah_s };
        #pragma unroll
        for (int pass = 0; pass < 3; ++pass) {
            const unsigned short* ap = aps[pass];
            const unsigned short* bp = bps[pass];
            #pragma unroll
            for (int k0 = 0; k0 < NN; k0 += 32) {
                short8 a0 = *reinterpret_cast<const short8*>(&ap[row * PB + k0 + kg]);
                short8 a1 = *reinterpret_cast<const short8*>(&ap[(row + 16) * PB + k0 + kg]);
                short8 bb0 = *reinterpret_cast<const short8*>(&bp[(f0 + row) * PB + k0 + kg]);
                short8 bb1 = *reinterpret_cast<const short8*>(&bp[(f0 + 16 + row) * PB + k0 + kg]);
                acc00 = __builtin_amdgcn_mfma_f32_16x16x32_bf16(a0, bb0, acc00, 0, 0, 0);
                acc01 = __builtin_amdgcn_mfma_f32_16x16x32_bf16(a0, bb1, acc01, 0, 0, 0);
                acc10 = __builtin_amdgcn_mfma_f32_16x16x32_bf16(a1, bb0, acc10, 0, 0, 0);
                acc11 = __builtin_amdgcn_mfma_f32_16x16x32_bf16(a1, bb1, acc11, 0, 0, 0);
            }
        }
        // C/D: col = lane&15, row = (lane>>4)*4 + q   [guide-verified m89/m91]
        float* outt = out + (size_t)t * NN * NN;
        int orow = (lane >> 4) * 4, col = lane & 15;
        #pragma unroll
        for (int q = 0; q < 4; ++q) {
            outt[(i0 + orow + q) * NN + f0 + col]           = acc00[q];
            outt[(i0 + orow + q) * NN + f0 + 16 + col]      = acc01[q];
            outt[(i0 + 16 + orow + q) * NN + f0 + col]      = acc10[q];
            outt[(i0 + 16 + orow + q) * NN + f0 + 16 + col] = acc11[q];
        }
    }
}

extern "C" void kernel_launch(void* const* d_in, const int* in_sizes, int n_in,
                              void* d_out, int out_size, void* d_ws, size_t ws_size,
                              hipStream_t stream) {
    const float* A = (const float*)d_in[0];
    const float* W = (const float*)d_in[1];
    const float* b = (const float*)d_in[2];
    float* out = (float*)d_out;
    gat_fused<<<dim3(64 * 4), dim3(256), 0, stream>>>(A, W, b, out);
}

// Round 3
// 10.957 us; speedup vs baseline: 1.6710x; 1.6710x over previous
//
#include <hip/hip_runtime.h>

#define NN 128

typedef __attribute__((ext_vector_type(8))) short short8;
typedef __attribute__((ext_vector_type(4))) float f32x4;

// XOR-swizzled LDS index (units = shorts). Row-major [rows][128] bf16;
// flips the 16B granule (bits 3..5 of short-index) by row&7 -> a 16-lane
// column-slice read (ds_read_b128, stride 256B) spreads across all 32 banks
// at 2-way max (free, m136). Preserves alignment of any 8B/16B access since
// only bits >=3 are flipped.
__device__ __forceinline__ int SWZ(int r, int cs) {
    return (r << 7) + (cs ^ ((r & 7) << 3));
}

__device__ __forceinline__ unsigned asu(float x) { return __float_as_uint(x); }
__device__ __forceinline__ float asf(unsigned u) { return __uint_as_float(u); }

// Fused GAT attention.
// grid = 512: t = bid & 63, ib = bid >> 6  (16 output rows per block).
//   -> all 8 i-blocks of one t share bid%8 (same XCD) for L2 reuse of A[t].
// block = 256 (4 waves); LDS 77 KB -> 2 blocks/CU -> 8 waves/CU.
__global__ __launch_bounds__(256, 2) void gat_fused(
    const float* __restrict__ A, const float* __restrict__ W,
    const float* __restrict__ b, float* __restrict__ out)
{
    __shared__ unsigned short Ah_s[NN * NN];   // bf16 hi of A[t,f,j]  (32 KB)
    __shared__ unsigned short Al_s[NN * NN];   // bf16 lo residual     (32 KB)
    __shared__ unsigned short ah_s[16 * NN];   // bf16 hi of alpha     (4 KB)
    __shared__ unsigned short al_s[16 * NN];   // bf16 lo residual     (4 KB)
    __shared__ float w_s[2 * NN];              // 1 KB
    __shared__ float part1_s[4 * NN];          // per-wave s1 partials (2 KB)
    __shared__ float part2_s[4 * NN];          // per-wave s2 partials (2 KB)

    const int tid  = threadIdx.x;
    const int lane = tid & 63;
    const int wid  = tid >> 6;
    const int t    = blockIdx.x & 63;
    const int i0   = (blockIdx.x >> 6) << 4;   // 16-row tile
    const float* At = A + (size_t)t * NN * NN;
    const float b0 = b[0];

    if (tid < 64)
        reinterpret_cast<float4*>(w_s)[tid] = reinterpret_cast<const float4*>(W)[tid];
    __syncthreads();

    // ---- stage A[t] -> (hi,lo) bf16 LDS (truncation split); fused fp32 s1/s2 partials ----
    {
        const float4* A4 = reinterpret_cast<const float4*>(At);
        float p1[4] = {0,0,0,0}, p2[4] = {0,0,0,0};
        #pragma unroll
        for (int it = 0; it < 16; ++it) {
            int e4 = it * 256 + tid;          // float4 index 0..4095
            int f  = e4 >> 5;                 // A row (the k of s1/s2)
            int cs = (e4 & 31) << 2;          // column (floats == shorts)
            float4 v = A4[e4];
            float wf1 = w_s[f], wf2 = w_s[NN + f];
            p1[0] += wf1 * v.x; p1[1] += wf1 * v.y; p1[2] += wf1 * v.z; p1[3] += wf1 * v.w;
            p2[0] += wf2 * v.x; p2[1] += wf2 * v.y; p2[2] += wf2 * v.z; p2[3] += wf2 * v.w;
            unsigned ux = asu(v.x), uy = asu(v.y), uz = asu(v.z), uw = asu(v.w);
            // hi = truncate to bf16 (top 16 bits); lo = exact residual, truncated
            float rx = v.x - asf(ux & 0xffff0000u);
            float ry = v.y - asf(uy & 0xffff0000u);
            float rz = v.z - asf(uz & 0xffff0000u);
            float rw = v.w - asf(uw & 0xffff0000u);
            uint2 hv, lv;
            hv.x = (ux >> 16) | (uy & 0xffff0000u);
            hv.y = (uz >> 16) | (uw & 0xffff0000u);
            lv.x = (asu(rx) >> 16) | (asu(ry) & 0xffff0000u);
            lv.y = (asu(rz) >> 16) | (asu(rw) & 0xffff0000u);
            int idx = SWZ(f, cs);
            *reinterpret_cast<uint2*>(&Ah_s[idx]) = hv;
            *reinterpret_cast<uint2*>(&Al_s[idx]) = lv;
        }
        // lane l and l^32 covered disjoint row sets of the same columns
        #pragma unroll
        for (int q = 0; q < 4; ++q) {
            p1[q] += __shfl_xor(p1[q], 32);
            p2[q] += __shfl_xor(p2[q], 32);
        }
        if (lane < 32) {                       // col = lane*4+q
            float4 v1 = { p1[0], p1[1], p1[2], p1[3] };
            float4 v2 = { p2[0], p2[1], p2[2], p2[3] };
            *reinterpret_cast<float4*>(&part1_s[wid * NN + lane * 4]) = v1;
            *reinterpret_cast<float4*>(&part2_s[wid * NN + lane * 4]) = v2;
        }
    }
    __syncthreads();

    // ---- softmax rows i0..i0+15 (16 lanes/row, 8 cols/lane); inline s1/s2 final sum ----
    {
        int r  = tid >> 4;                    // 0..15 local row
        int jj = tid & 15;                    // cols jj*8 .. jj*8+7
        float s1v = part1_s[i0 + r] + part1_s[NN + i0 + r]
                  + part1_s[2 * NN + i0 + r] + part1_s[3 * NN + i0 + r] + b0;
        float s2v[8] = {0,0,0,0,0,0,0,0};
        #pragma unroll
        for (int w = 0; w < 4; ++w) {
            float4 a = *reinterpret_cast<const float4*>(&part2_s[w * NN + jj * 8]);
            float4 c = *reinterpret_cast<const float4*>(&part2_s[w * NN + jj * 8 + 4]);
            s2v[0] += a.x; s2v[1] += a.y; s2v[2] += a.z; s2v[3] += a.w;
            s2v[4] += c.x; s2v[5] += c.y; s2v[6] += c.z; s2v[7] += c.w;
        }
        float ev[8];
        float m = -3.4e38f;
        #pragma unroll
        for (int c = 0; c < 8; ++c) {
            float x = s1v + s2v[c];
            x = (x >= 0.f) ? x : 0.2f * x;    // leaky_relu 0.2
            ev[c] = x;
            m = fmaxf(m, x);
        }
        m = fmaxf(m, __shfl_xor(m, 1));
        m = fmaxf(m, __shfl_xor(m, 2));
        m = fmaxf(m, __shfl_xor(m, 4));
        m = fmaxf(m, __shfl_xor(m, 8));
        float s = 0.f;
        #pragma unroll
        for (int c = 0; c < 8; ++c) { ev[c] = __expf(ev[c] - m); s += ev[c]; }
        s += __shfl_xor(s, 1);
        s += __shfl_xor(s, 2);
        s += __shfl_xor(s, 4);
        s += __shfl_xor(s, 8);
        float inv = 1.0f / s;
        unsigned h[4], l[4];
        #pragma unroll
        for (int c = 0; c < 8; c += 2) {
            float v0 = ev[c] * inv, v1 = ev[c + 1] * inv;
            unsigned u0 = asu(v0), u1 = asu(v1);
            float r0 = v0 - asf(u0 & 0xffff0000u);
            float r1 = v1 - asf(u1 & 0xffff0000u);
            h[c >> 1] = (u0 >> 16) | (u1 & 0xffff0000u);
            l[c >> 1] = (asu(r0) >> 16) | (asu(r1) & 0xffff0000u);
        }
        int idx = SWZ(r, jj * 8);
        uint4 hv = { h[0], h[1], h[2], h[3] };
        uint4 lv = { l[0], l[1], l[2], l[3] };
        *reinterpret_cast<uint4*>(&ah_s[idx]) = hv;
        *reinterpret_cast<uint4*>(&al_s[idx]) = lv;
    }
    __syncthreads();

    // ---- PV via MFMA: out(16 x 128) = alpha(16 x 128) @ B(128 x 128), B[j,f]=A[t,f,j]
    // passes: ah*Ah + ah*Al + al*Ah  (al*Al ~ 2^-16, dropped)
    {
        int f0 = wid * 32;                    // wave's 32 output cols
        int ar = lane & 15;
        int kg = (lane >> 4) << 3;
        f32x4 acc0 = {0.f,0.f,0.f,0.f}, acc1 = {0.f,0.f,0.f,0.f};
        const unsigned short* aps[3] = { ah_s, ah_s, al_s };
        const unsigned short* bps[3] = { Ah_s, Al_s, Ah_s };
        #pragma unroll
        for (int pass = 0; pass < 3; ++pass) {
            const unsigned short* ap = aps[pass];
            const unsigned short* bp = bps[pass];
            #pragma unroll
            for (int k0 = 0; k0 < NN; k0 += 32) {
                short8 a  = *reinterpret_cast<const short8*>(&ap[SWZ(ar, k0 + kg)]);
                short8 bb0 = *reinterpret_cast<const short8*>(&bp[SWZ(f0 + ar, k0 + kg)]);
                short8 bb1 = *reinterpret_cast<const short8*>(&bp[SWZ(f0 + 16 + ar, k0 + kg)]);
                acc0 = __builtin_amdgcn_mfma_f32_16x16x32_bf16(a, bb0, acc0, 0, 0, 0);
                acc1 = __builtin_amdgcn_mfma_f32_16x16x32_bf16(a, bb1, acc1, 0, 0, 0);
            }
        }
        // C/D: col = lane&15, row = (lane>>4)*4 + q
        float* outt = out + (size_t)t * NN * NN;
        int orow = i0 + ((lane >> 4) << 2);
        int col  = lane & 15;
        #pragma unroll
        for (int q = 0; q < 4; ++q) {
            outt[(orow + q) * NN + f0 + col]      = acc0[q];
            outt[(orow + q) * NN + f0 + 16 + col] = acc1[q];
        }
    }
}

extern "C" void kernel_launch(void* const* d_in, const int* in_sizes, int n_in,
                              void* d_out, int out_size, void* d_ws, size_t ws_size,
                              hipStream_t stream) {
    const float* A = (const float*)d_in[0];
    const float* W = (const float*)d_in[1];
    const float* b = (const float*)d_in[2];
    float* out = (float*)d_out;
    gat_fused<<<dim3(512), dim3(256), 0, stream>>>(A, W, b, out);
}